// Round 15
// baseline (85.641 us; speedup 1.0000x reference)
//
#include <hip/hip_runtime.h>
#include <math.h>

#define Bb 4
#define Mm 8192
#define Kk 64
#define Cc 32
#define Pp 28

#define OFF_PSDF  (Bb*Mm)                          // 32768
#define OFF_INTER (Bb*Mm + Bb*Mm*Kk)               // 2129920
#define OFF_SD    (Bb*Mm + Bb*Mm*Kk + Bb*Mm*Cc)    // 3178496

#define W40    57.707801635558535f      // 40*log2(e)
#define NL2_40 (-0.017328679513998632f) // -ln2/40
#define S75    108.20212806667225f      // 75*log2(e)
#define EPS_OCC 1e-6f

// measurement knob: phase-1 min-loop repeated REP times (idempotent -> outputs
// bit-identical). T_ph1 = (dur - dur_at_REP1) / (REP-1).
#define REP 4

#define OCC_STRIDE 36
#define TBL_OFF    2304

struct Rad12 { float v[12]; };

__device__ __forceinline__ float fexp2(float x){ return __builtin_amdgcn_exp2f(x); }
__device__ __forceinline__ float frcp(float x){ return __builtin_amdgcn_rcpf(x); }

// ---------------- Kernel 0: expand curves + params + (k,c) sums ------------
__global__ __launch_bounds__(256)
void curve_prep(const float* __restrict__ pp, const float* __restrict__ iw_g,
                Rad12 rad,
                float* __restrict__ ws_c, float* __restrict__ params_ws,
                float2* __restrict__ st_ws)
{
    const int g = blockIdx.x * 256 + threadIdx.x;   // 16384 threads
    const int k = g & 63;
    const int n = (g >> 6) & 63;
    const int b = g >> 12;

#define PP(p) pp[((b * Pp) + (p)) * Kk + k]

    const int s  = n >> 4;
    const int it = n & 15;
    const float t = (float)it * 0.0625f;            // exact i/16
    const int s1 = (s + 1) & 3;

    float r0 = fabsf(PP(8 + 3 * s + 0));
    float r1 = fabsf(PP(8 + 3 * s + 1));
    float r2 = fabsf(PP(8 + 3 * s + 2));
    float r3 = fabsf(PP(8 + 3 * s1 + 0));
    float w1 = fabsf(PP(20 + 2 * s + 0));
    float w2 = fabsf(PP(20 + 2 * s + 1));

    float a0 = rad.v[3 * s + 0], a1 = rad.v[3 * s + 1];
    float a2 = rad.v[3 * s + 2], a3 = rad.v[3 * s1 + 0];

    float P0x = cosf(a0) * r0, P0y = sinf(a0) * r0;
    float P1x = cosf(a1) * r1, P1y = sinf(a1) * r1;
    float P2x = cosf(a2) * r2, P2y = sinf(a2) * r2;
    float P3x = cosf(a3) * r3, P3y = sinf(a3) * r3;

    float omt = 1.0f - t;
    float b0 = omt * omt * omt;
    float b1 = (3.0f * t) * (omt * omt);
    float b2 = (3.0f * (t * t)) * omt;
    float b3 = t * t * t;
    float bw1 = b1 * w1, bw2 = b2 * w2;
    float den = ((b0 + bw1) + bw2) + b3;
    float nx  = ((b0 * P0x + bw1 * P1x) + bw2 * P2x) + b3 * P3x;
    float ny  = ((b0 * P0y + bw1 * P1y) + bw2 * P2y) + b3 * P3y;

    float cx = nx / den, cy = ny / den;
    const int j = n >> 1, h = n & 1;
    float* base = ws_c + (((b * 32 + j) * 64) + k) * 4;
    base[h]     = -2.0f * cx;
    base[2 + h] = -2.0f * cy;

    if (n < 8) {
        float val;
        if (n < 4) {
            float q0 = PP(0), q1 = PP(1), q2 = PP(2), q3 = PP(3);
            float nrm = sqrtf(q0 * q0 + q1 * q1 + q2 * q2 + q3 * q3);
            val = PP(n) / nrm;
        } else {
            val = PP(n);        // p=4..6 trans, p=7 height
        }
        params_ws[(b * Kk + k) * 8 + n] = val;
    }
#undef PP

    if (blockIdx.x == 0 && threadIdx.x < 128) {
        const int tb = threadIdx.x >> 5, tc = threadIdx.x & 31;
        float S = 0.0f, T = 0.0f;
        for (int kk = 0; kk < 64; ++kk) {
            float w   = iw_g[tb * 2048 + kk * 32 + tc];
            float b40 = (w - 1.0f) * W40;
            float e   = fexp2(b40);
            S += e;
            T  = fmaf(e, b40, T);
        }
        st_ws[threadIdx.x] = make_float2(S, T);
    }
}

// ---------------- Kernel 1: fused main (REP-instrumented phase 1) ----------
__global__ __launch_bounds__(512)
void csg_main(const float* __restrict__ pts, const float* __restrict__ iw_g,
              const float* __restrict__ uw_g, const int* __restrict__ flag,
              const float* __restrict__ ws_c, const float* __restrict__ params_ws,
              const float2* __restrict__ st_ws, float* __restrict__ out)
{
    __shared__ __align__(16) float s_pool[8192];   // 32 KB exactly

    const int tid = threadIdx.x;
    const int bid = blockIdx.x;
    const int b   = bid >> 8;                  // 256 blocks per batch
    const int m0  = (bid & 255) << 5;          // 32 points per block

    float wreg[4];
    {
        const float4* cs = (const float4*)(ws_c + (size_t)b * 8192);
        float4* cd = (float4*)s_pool;
#pragma unroll
        for (int i = 0; i < 4; ++i) cd[tid + i * 512] = cs[tid + i * 512];
#pragma unroll
        for (int i = 0; i < 4; ++i) wreg[i] = iw_g[b * 2048 + tid + i * 512];
    }
    __syncthreads();

    const int wid  = tid >> 6;
    const int lane = tid & 63;
    const int k    = lane;
    const int pt0  = b * Mm + m0 + (wid << 2);   // 4 pts per wave

    const float4* prm4 = (const float4*)(params_ws + ((b << 6) + k) * 8);
    float4 q4 = prm4[0];   // qw qx qy qz (normalized)
    float4 t4 = prm4[1];   // tx ty tz height

    const float4* pts4 = (const float4*)(pts + (size_t)pt0 * 3);
    float4 A = pts4[0], Bv = pts4[1], Cv = pts4[2];
    float pxs[4] = {A.x, A.w, Bv.z, Cv.y};
    float pys[4] = {A.y, Bv.x, Bv.w, Cv.z};
    float pzs[4] = {A.z, Bv.y, Cv.x, Cv.w};

    float px4[4], py4[4], plzv[4], psq[4];
    {
        float vx = -q4.y, vy = -q4.z, vz = -q4.w, qw = q4.x;
#pragma unroll
        for (int p = 0; p < 4; ++p) {
            float px = pxs[p] - t4.x, py = pys[p] - t4.y, pz = pzs[p] - t4.z;
            float t1x = 2.0f * (vy * pz - vz * py);
            float t1y = 2.0f * (vz * px - vx * pz);
            float t1z = 2.0f * (vx * py - vy * px);
            float plx = px + qw * t1x + (vy * t1z - vz * t1y);
            float ply = py + qw * t1y + (vz * t1x - vx * t1z);
            plzv[p] = pz + qw * t1z + (vx * t1y - vy * t1x);
            psq[p]  = plx * plx + ply * ply;
            px4[p]  = 4.0f * plx;                 // exact pow2 scale
            py4[p]  = 4.0f * ply;
        }
    }

    // phase-1 min scan, repeated REP times (idempotent; keep-alive defeats CSE)
    float best4[4] = {1e30f, 1e30f, 1e30f, 1e30f};
    float bcsq4[4] = {0.0f, 0.0f, 0.0f, 0.0f};
#pragma unroll 1
    for (int rep = 0; rep < REP; ++rep) {
        const float4* cdp = (const float4*)&s_pool[k * 4];   // j*1024B imm
#pragma unroll 4
        for (int j = 0; j < 32; ++j) {
            float4 cd = cdp[j * 64];       // {m2x_e, m2x_o, m2y_e, m2y_o}
            float cq4x = fmaf(cd.x, cd.x, cd.z * cd.z);
            float cq4y = fmaf(cd.y, cd.y, cd.w * cd.w);
#pragma unroll
            for (int p = 0; p < 4; ++p) {
                float da = fmaf(cd.x, px4[p], fmaf(cd.z, py4[p], cq4x));
                if (da < best4[p]) { best4[p] = da; bcsq4[p] = cq4x; }
                float db = fmaf(cd.y, px4[p], fmaf(cd.w, py4[p], cq4y));
                if (db < best4[p]) { best4[p] = db; bcsq4[p] = cq4y; }
            }
        }
#pragma unroll
        for (int p = 0; p < 4; ++p)
            asm volatile("" : "+v"(best4[p]), "+v"(bcsq4[p]));
    }

    float occ[4];
    unsigned long long mu = 0ull;
#pragma unroll
    for (int p = 0; p < 4; ++p) {
        float d2    = psq[p] + 0.25f * best4[p];        // == psq + best exact
        float bq    = 0.25f * bcsq4[p];                 // == bcsq exact
        float ud    = sqrtf(fmaxf(d2, 0.0f) + 1e-12f);
        float sgn   = (psq[p] <= bq) ? -1.0f : 1.0f;    // == sqrt-compare
        float sdf2d = sgn * ud;
        float dzv   = fabsf(plzv[p]) - t4.w;
        float inner = fminf(fmaxf(sdf2d, dzv), 0.0f);
        float r1m   = fmaxf(sdf2d, 0.0f), r2m = fmaxf(dzv, 0.0f);
        float psdf  = inner + sqrtf(r1m * r1m + r2m * r2m + 1e-12f);
        out[OFF_PSDF + (pt0 + p) * Kk + k] = psdf;
        out[OFF_SD   + (pt0 + p) * Kk + k] = ud;
        occ[p]  = frcp(1.0f + fexp2(S75 * psdf));   // sigmoid(-75*psdf)
        mu |= __ballot(occ[p] > EPS_OCC);           // union over the 4 points
    }

    const int c = lane & 31;
    float2 s0t0 = st_ws[b * 32 + c];

    __syncthreads();
    {
        *(float4*)&s_pool[k * OCC_STRIDE + (wid << 2)] =
            make_float4(occ[0], occ[1], occ[2], occ[3]);
#pragma unroll
        for (int i = 0; i < 4; ++i) {
            int idx = tid + i * 512;               // (k,c) = idx>>5, idx&31
            float w = wreg[i];
            ((float2*)&s_pool[TBL_OFF])[idx] = make_float2(w * (-W40), (w - 1.0f) * W40);
        }
    }
    __syncthreads();

    const int training = flag[0];
    const float2* tbl = (const float2*)&s_pool[TBL_OFF];
    const int ows = wid << 2;

    float inter[4];
    if (training) {
        float sw[4]  = {s0t0.x, s0t0.x, s0t0.x, s0t0.x};
        float swp[4] = {s0t0.y, s0t0.y, s0t0.y, s0t0.y};
        unsigned long long m = mu;
        while (m) {
            int kk = __builtin_ctzll(m); m &= m - 1;
            float4 o4 = *(const float4*)&s_pool[kk * OCC_STRIDE + ows];
            float2 wv = tbl[kk * 32 + c];
            float e0  = fexp2(wv.y);
            float e0b = e0 * wv.y;
            float os[4] = {o4.x, o4.y, o4.z, o4.w};
#pragma unroll
            for (int p = 0; p < 4; ++p) {
                float pre = fmaf(wv.x, os[p], wv.y);
                float e   = fexp2(pre);
                sw[p]  += (e - e0);
                swp[p] += fmaf(e, pre, -e0b);
            }
        }
#pragma unroll
        for (int p = 0; p < 4; ++p)
            inter[p] = swp[p] * frcp(sw[p]) * NL2_40;
    } else {
        float mx[4] = {-1e30f, -1e30f, -1e30f, -1e30f};
#pragma unroll 8
        for (int kk = 0; kk < 64; ++kk) {
            float4 o4 = *(const float4*)&s_pool[kk * OCC_STRIDE + ows];
            float2 wv = tbl[kk * 32 + c];
            float os[4] = {o4.x, o4.y, o4.z, o4.w};
#pragma unroll
            for (int p = 0; p < 4; ++p)
                mx[p] = fmaxf(mx[p], fmaf(wv.x, os[p], wv.y));
        }
#pragma unroll
        for (int p = 0; p < 4; ++p)
            inter[p] = mx[p] * NL2_40;
    }

    if (lane < Cc) {
#pragma unroll
        for (int p = 0; p < 4; ++p)
            out[OFF_INTER + (pt0 + p) * Cc + c] = inter[p];
    }

    float uwv = uw_g[b * Cc + c];
    float resv[4];
    if (training) {
#pragma unroll
        for (int p = 0; p < 4; ++p) {
            float pu  = uwv * inter[p];
            float e   = fexp2(W40 * pu);
            float num = e * pu, den = e;
#pragma unroll
            for (int msk = 16; msk >= 1; msk >>= 1) {
                num += __shfl_xor(num, msk, 64);
                den += __shfl_xor(den, msk, 64);
            }
            resv[p] = num * frcp(den);
        }
    } else {
#pragma unroll
        for (int p = 0; p < 4; ++p) {
            float pu = uwv * inter[p];
#pragma unroll
            for (int msk = 16; msk >= 1; msk >>= 1)
                pu = fmaxf(pu, __shfl_xor(pu, msk, 64));
            resv[p] = pu;
        }
    }
    if (lane == 0)
        *(float4*)(out + pt0) = make_float4(resv[0], resv[1], resv[2], resv[3]);
}

// ---------------- host launch ----------------------------------------------
extern "C" void kernel_launch(void* const* d_in, const int* in_sizes, int n_in,
                              void* d_out, int out_size, void* d_ws, size_t ws_size,
                              hipStream_t stream)
{
    const float* pts  = (const float*)d_in[0];
    const float* pp   = (const float*)d_in[1];
    const float* iw   = (const float*)d_in[2];
    const float* uw   = (const float*)d_in[3];
    const int*   flag = (const int*)d_in[4];
    float* out = (float*)d_out;

    float*  ws_c   = (float*)d_ws;             // 32768 floats (128 KB)
    float*  params = ws_c + 32768;             // 2048 floats (8 KB)
    float2* st_ws  = (float2*)(params + 2048); // 128 float2 (1 KB)

    Rad12 rad;
    const double th = M_PI * 2.0 / 16.0 + atan(tan(2.0 * M_PI / 16.0) / 3.0);
    for (int i = 0; i < 4; ++i) {
        double base = 2.0 * M_PI / 4.0 * (double)i;
        rad.v[3 * i + 0] = (float)base;
        rad.v[3 * i + 1] = (float)(base + th);
        rad.v[3 * i + 2] = (float)(2.0 * M_PI / 4.0 * (double)(i + 1) - th);
    }

    curve_prep<<<64, 256, 0, stream>>>(pp, iw, rad, ws_c, params, st_ws);
    csg_main<<<Bb * Mm / 32, 512, 0, stream>>>(pts, iw, uw, flag,
                                               ws_c, params, st_ws, out);
}

// Round 16
// 39.933 us; speedup vs baseline: 2.1446x; 2.1446x over previous
//
#include <hip/hip_runtime.h>
#include <math.h>

#define Bb 4
#define Mm 8192
#define Kk 64
#define Cc 32
#define Pp 28

#define OFF_PSDF  (Bb*Mm)                          // 32768
#define OFF_INTER (Bb*Mm + Bb*Mm*Kk)               // 2129920
#define OFF_SD    (Bb*Mm + Bb*Mm*Kk + Bb*Mm*Cc)    // 3178496

#define W40    57.707801635558535f      // 40*log2(e)
#define NL2_40 (-0.017328679513998632f) // -ln2/40
#define S75    108.20212806667225f      // 75*log2(e)
#define EPS_OCC 1e-6f

#define OCC_STRIDE 36
#define TBL_OFF    2304

struct Rad12 { float v[12]; };

__device__ __forceinline__ float fexp2(float x){ return __builtin_amdgcn_exp2f(x); }
__device__ __forceinline__ float frcp(float x){ return __builtin_amdgcn_rcpf(x); }

// ---------------- Kernel 0: expand curves + params + (k,c) sums ------------
__global__ __launch_bounds__(256)
void curve_prep(const float* __restrict__ pp, const float* __restrict__ iw_g,
                Rad12 rad,
                float* __restrict__ ws_c, float* __restrict__ params_ws,
                float2* __restrict__ st_ws)
{
    const int g = blockIdx.x * 256 + threadIdx.x;   // 16384 threads
    const int k = g & 63;
    const int n = (g >> 6) & 63;
    const int b = g >> 12;

#define PP(p) pp[((b * Pp) + (p)) * Kk + k]

    const int s  = n >> 4;
    const int it = n & 15;
    const float t = (float)it * 0.0625f;            // exact i/16
    const int s1 = (s + 1) & 3;

    float r0 = fabsf(PP(8 + 3 * s + 0));
    float r1 = fabsf(PP(8 + 3 * s + 1));
    float r2 = fabsf(PP(8 + 3 * s + 2));
    float r3 = fabsf(PP(8 + 3 * s1 + 0));
    float w1 = fabsf(PP(20 + 2 * s + 0));
    float w2 = fabsf(PP(20 + 2 * s + 1));

    float a0 = rad.v[3 * s + 0], a1 = rad.v[3 * s + 1];
    float a2 = rad.v[3 * s + 2], a3 = rad.v[3 * s1 + 0];

    float P0x = cosf(a0) * r0, P0y = sinf(a0) * r0;
    float P1x = cosf(a1) * r1, P1y = sinf(a1) * r1;
    float P2x = cosf(a2) * r2, P2y = sinf(a2) * r2;
    float P3x = cosf(a3) * r3, P3y = sinf(a3) * r3;

    float omt = 1.0f - t;
    float b0 = omt * omt * omt;
    float b1 = (3.0f * t) * (omt * omt);
    float b2 = (3.0f * (t * t)) * omt;
    float b3 = t * t * t;
    float bw1 = b1 * w1, bw2 = b2 * w2;
    float den = ((b0 + bw1) + bw2) + b3;
    float nx  = ((b0 * P0x + bw1 * P1x) + bw2 * P2x) + b3 * P3x;
    float ny  = ((b0 * P0y + bw1 * P1y) + bw2 * P2y) + b3 * P3y;

    float cx = nx / den, cy = ny / den;
    const int j = n >> 1, h = n & 1;
    float* base = ws_c + (((b * 32 + j) * 64) + k) * 4;
    base[h]     = -2.0f * cx;
    base[2 + h] = -2.0f * cy;

    if (n < 8) {
        float val;
        if (n < 4) {
            float q0 = PP(0), q1 = PP(1), q2 = PP(2), q3 = PP(3);
            float nrm = sqrtf(q0 * q0 + q1 * q1 + q2 * q2 + q3 * q3);
            val = PP(n) / nrm;
        } else {
            val = PP(n);        // p=4..6 trans, p=7 height
        }
        params_ws[(b * Kk + k) * 8 + n] = val;
    }
#undef PP

    if (blockIdx.x == 0 && threadIdx.x < 128) {
        const int tb = threadIdx.x >> 5, tc = threadIdx.x & 31;
        float S = 0.0f, T = 0.0f;
        for (int kk = 0; kk < 64; ++kk) {
            float w   = iw_g[tb * 2048 + kk * 32 + tc];
            float b40 = (w - 1.0f) * W40;
            float e   = fexp2(b40);
            S += e;
            T  = fmaf(e, b40, T);
        }
        st_ws[threadIdx.x] = make_float2(S, T);
    }
}

// ---------------- Kernel 1: fused main ------------------------------------
// block = 512 threads = 8 waves; each wave = 4 points (ph1 lane = primitive k).
// LDS EXACTLY 32 KB. No __launch_bounds__ min-waves arg (R9-R11: caps => RA
// spill storms). unroll 4 bounds in-flight ds_reads.
// Phase 2: SPLIT-K across lane halves (lo: k<32 seeded with S0T0, hi: k>=32
// seeded 0), one shfl_xor(32) combine — halves phase-2 work vs R14.
__global__ __launch_bounds__(512)
void csg_main(const float* __restrict__ pts, const float* __restrict__ iw_g,
              const float* __restrict__ uw_g, const int* __restrict__ flag,
              const float* __restrict__ ws_c, const float* __restrict__ params_ws,
              const float2* __restrict__ st_ws, float* __restrict__ out)
{
    __shared__ __align__(16) float s_pool[8192];   // 32 KB exactly

    const int tid = threadIdx.x;
    const int bid = blockIdx.x;
    const int b   = bid >> 8;                  // 256 blocks per batch
    const int m0  = (bid & 255) << 5;          // 32 points per block

    float wreg[4];
    {
        const float4* cs = (const float4*)(ws_c + (size_t)b * 8192);
        float4* cd = (float4*)s_pool;
#pragma unroll
        for (int i = 0; i < 4; ++i) cd[tid + i * 512] = cs[tid + i * 512];
#pragma unroll
        for (int i = 0; i < 4; ++i) wreg[i] = iw_g[b * 2048 + tid + i * 512];
    }
    __syncthreads();

    const int wid  = tid >> 6;
    const int lane = tid & 63;
    const int k    = lane;
    const int pt0  = b * Mm + m0 + (wid << 2);   // 4 pts per wave

    const float4* prm4 = (const float4*)(params_ws + ((b << 6) + k) * 8);
    float4 q4 = prm4[0];   // qw qx qy qz (normalized)
    float4 t4 = prm4[1];   // tx ty tz height

    const float4* pts4 = (const float4*)(pts + (size_t)pt0 * 3);
    float4 A = pts4[0], Bv = pts4[1], Cv = pts4[2];
    float pxs[4] = {A.x, A.w, Bv.z, Cv.y};
    float pys[4] = {A.y, Bv.x, Bv.w, Cv.z};
    float pzs[4] = {A.z, Bv.y, Cv.x, Cv.w};

    float px4[4], py4[4], plzv[4], psq[4];
    {
        float vx = -q4.y, vy = -q4.z, vz = -q4.w, qw = q4.x;
#pragma unroll
        for (int p = 0; p < 4; ++p) {
            float px = pxs[p] - t4.x, py = pys[p] - t4.y, pz = pzs[p] - t4.z;
            float t1x = 2.0f * (vy * pz - vz * py);
            float t1y = 2.0f * (vz * px - vx * pz);
            float t1z = 2.0f * (vx * py - vy * px);
            float plx = px + qw * t1x + (vy * t1z - vz * t1y);
            float ply = py + qw * t1y + (vz * t1x - vx * t1z);
            plzv[p] = pz + qw * t1z + (vx * t1y - vy * t1x);
            psq[p]  = plx * plx + ply * ply;
            px4[p]  = 4.0f * plx;                 // exact pow2 scale
            py4[p]  = 4.0f * ply;
        }
    }

    // 4x-scaled: cq4 = 4*csq = fma(m2x,m2x,m2y^2) exact;
    // d4 = 4*(csq - 2*dot) = fma(m2x, 4px, fma(m2y, 4py, cq4)) exact.
    float best4[4] = {1e30f, 1e30f, 1e30f, 1e30f};
    float bcsq4[4] = {0.0f, 0.0f, 0.0f, 0.0f};
    {
        const float4* cdp = (const float4*)&s_pool[k * 4];   // j*1024B imm
#pragma unroll 4
        for (int j = 0; j < 32; ++j) {
            float4 cd = cdp[j * 64];       // {m2x_e, m2x_o, m2y_e, m2y_o}
            float cq4x = fmaf(cd.x, cd.x, cd.z * cd.z);
            float cq4y = fmaf(cd.y, cd.y, cd.w * cd.w);
#pragma unroll
            for (int p = 0; p < 4; ++p) {
                float da = fmaf(cd.x, px4[p], fmaf(cd.z, py4[p], cq4x));
                if (da < best4[p]) { best4[p] = da; bcsq4[p] = cq4x; }
                float db = fmaf(cd.y, px4[p], fmaf(cd.w, py4[p], cq4y));
                if (db < best4[p]) { best4[p] = db; bcsq4[p] = cq4y; }
            }
        }
    }

    float occ[4];
    unsigned long long mu = 0ull;
#pragma unroll
    for (int p = 0; p < 4; ++p) {
        float d2    = psq[p] + 0.25f * best4[p];        // == psq + best exact
        float bq    = 0.25f * bcsq4[p];                 // == bcsq exact
        float ud    = sqrtf(fmaxf(d2, 0.0f) + 1e-12f);
        float sgn   = (psq[p] <= bq) ? -1.0f : 1.0f;    // == sqrt-compare
        float sdf2d = sgn * ud;
        float dzv   = fabsf(plzv[p]) - t4.w;
        float inner = fminf(fmaxf(sdf2d, dzv), 0.0f);
        float r1m   = fmaxf(sdf2d, 0.0f), r2m = fmaxf(dzv, 0.0f);
        float psdf  = inner + sqrtf(r1m * r1m + r2m * r2m + 1e-12f);
        out[OFF_PSDF + (pt0 + p) * Kk + k] = psdf;
        out[OFF_SD   + (pt0 + p) * Kk + k] = ud;
        occ[p]  = frcp(1.0f + fexp2(S75 * psdf));   // sigmoid(-75*psdf)
        mu |= __ballot(occ[p] > EPS_OCC);           // union over the 4 points
    }

    const int c  = lane & 31;
    const int hi = lane >> 5;                      // 0 = k<32, 1 = k>=32
    float2 s0t0 = st_ws[b * 32 + c];

    __syncthreads();
    {
        *(float4*)&s_pool[k * OCC_STRIDE + (wid << 2)] =
            make_float4(occ[0], occ[1], occ[2], occ[3]);
#pragma unroll
        for (int i = 0; i < 4; ++i) {
            int idx = tid + i * 512;               // (k,c) = idx>>5, idx&31
            float w = wreg[i];
            ((float2*)&s_pool[TBL_OFF])[idx] = make_float2(w * (-W40), (w - 1.0f) * W40);
        }
    }
    __syncthreads();

    // ============ Phase 2: split-k across halves, lane = (hi, c) ==========
    const int training = flag[0];
    const float2* tbl = (const float2*)&s_pool[TBL_OFF];
    const int ows = wid << 2;
    const int kb  = hi << 5;

    float inter[4];
    if (training) {
        // lo half seeds S0T0, hi half seeds 0; cross-add yields full sum.
        float sw[4], swp[4];
#pragma unroll
        for (int p = 0; p < 4; ++p) {
            sw[p]  = hi ? 0.0f : s0t0.x;
            swp[p] = hi ? 0.0f : s0t0.y;
        }
        unsigned long long m = hi ? (mu >> 32) : (mu & 0xFFFFFFFFull);
        while (m) {
            int kk = __builtin_ctzll(m) + kb; m &= m - 1;
            float4 o4 = *(const float4*)&s_pool[kk * OCC_STRIDE + ows]; // bcast/half
            float2 wv = tbl[kk * 32 + c];                               // {a, b}
            float e0  = fexp2(wv.y);
            float e0b = e0 * wv.y;
            float os[4] = {o4.x, o4.y, o4.z, o4.w};
#pragma unroll
            for (int p = 0; p < 4; ++p) {
                float pre = fmaf(wv.x, os[p], wv.y);    // -40*log2e * pre_i
                float e   = fexp2(pre);                 // in (0,1]: safe
                sw[p]  += (e - e0);
                swp[p] += fmaf(e, pre, -e0b);
            }
        }
#pragma unroll
        for (int p = 0; p < 4; ++p) {
            float swt  = sw[p]  + __shfl_xor(sw[p], 32, 64);
            float swpt = swp[p] + __shfl_xor(swp[p], 32, 64);
            inter[p] = swpt * frcp(swt) * NL2_40;
        }
    } else {
        float mx[4] = {-1e30f, -1e30f, -1e30f, -1e30f};
#pragma unroll 8
        for (int j = 0; j < 32; ++j) {
            int kk = kb + j;
            float4 o4 = *(const float4*)&s_pool[kk * OCC_STRIDE + ows];
            float2 wv = tbl[kk * 32 + c];
            float os[4] = {o4.x, o4.y, o4.z, o4.w};
#pragma unroll
            for (int p = 0; p < 4; ++p)
                mx[p] = fmaxf(mx[p], fmaf(wv.x, os[p], wv.y));
        }
#pragma unroll
        for (int p = 0; p < 4; ++p) {
            float m2 = fmaxf(mx[p], __shfl_xor(mx[p], 32, 64));
            inter[p] = m2 * NL2_40;                 // min_k pre_i
        }
    }

    if (lane < Cc) {
#pragma unroll
        for (int p = 0; p < 4; ++p)
            out[OFF_INTER + (pt0 + p) * Cc + c] = inter[p];
    }

    // ---- union over c (softmax / max) ----
    float uwv = uw_g[b * Cc + c];
    float resv[4];
    if (training) {
#pragma unroll
        for (int p = 0; p < 4; ++p) {
            float pu  = uwv * inter[p];
            float e   = fexp2(W40 * pu);             // exp(40*pre_u) <= e^40
            float num = e * pu, den = e;
#pragma unroll
            for (int msk = 16; msk >= 1; msk >>= 1) {
                num += __shfl_xor(num, msk, 64);
                den += __shfl_xor(den, msk, 64);
            }
            resv[p] = num * frcp(den);
        }
    } else {
#pragma unroll
        for (int p = 0; p < 4; ++p) {
            float pu = uwv * inter[p];
#pragma unroll
            for (int msk = 16; msk >= 1; msk >>= 1)
                pu = fmaxf(pu, __shfl_xor(pu, msk, 64));
            resv[p] = pu;
        }
    }
    if (lane == 0)
        *(float4*)(out + pt0) = make_float4(resv[0], resv[1], resv[2], resv[3]);
}

// ---------------- host launch ----------------------------------------------
extern "C" void kernel_launch(void* const* d_in, const int* in_sizes, int n_in,
                              void* d_out, int out_size, void* d_ws, size_t ws_size,
                              hipStream_t stream)
{
    const float* pts  = (const float*)d_in[0];
    const float* pp   = (const float*)d_in[1];
    const float* iw   = (const float*)d_in[2];
    const float* uw   = (const float*)d_in[3];
    const int*   flag = (const int*)d_in[4];
    float* out = (float*)d_out;

    float*  ws_c   = (float*)d_ws;             // 32768 floats (128 KB)
    float*  params = ws_c + 32768;             // 2048 floats (8 KB)
    float2* st_ws  = (float2*)(params + 2048); // 128 float2 (1 KB)

    Rad12 rad;
    const double th = M_PI * 2.0 / 16.0 + atan(tan(2.0 * M_PI / 16.0) / 3.0);
    for (int i = 0; i < 4; ++i) {
        double base = 2.0 * M_PI / 4.0 * (double)i;
        rad.v[3 * i + 0] = (float)base;
        rad.v[3 * i + 1] = (float)(base + th);
        rad.v[3 * i + 2] = (float)(2.0 * M_PI / 4.0 * (double)(i + 1) - th);
    }

    curve_prep<<<64, 256, 0, stream>>>(pp, iw, rad, ws_c, params, st_ws);
    csg_main<<<Bb * Mm / 32, 512, 0, stream>>>(pts, iw, uw, flag,
                                               ws_c, params, st_ws, out);
}

// Round 17
// 39.683 us; speedup vs baseline: 2.1581x; 1.0063x over previous
//
#include <hip/hip_runtime.h>
#include <math.h>

#define Bb 4
#define Mm 8192
#define Kk 64
#define Cc 32
#define Pp 28

#define OFF_PSDF  (Bb*Mm)                          // 32768
#define OFF_INTER (Bb*Mm + Bb*Mm*Kk)               // 2129920
#define OFF_SD    (Bb*Mm + Bb*Mm*Kk + Bb*Mm*Cc)    // 3178496

#define W40    57.707801635558535f      // 40*log2(e)
#define NL2_40 (-0.017328679513998632f) // -ln2/40
#define S75    108.20212806667225f      // 75*log2(e)
#define EPS_OCC 1e-6f

struct Rad12 { float v[12]; };

__device__ __forceinline__ float fexp2(float x){ return __builtin_amdgcn_exp2f(x); }
__device__ __forceinline__ float frcp(float x){ return __builtin_amdgcn_rcpf(x); }
__device__ __forceinline__ float bperm(int idx4, float v){
    return __int_as_float(__builtin_amdgcn_ds_bpermute(idx4, __float_as_int(v)));
}

// ---------------- Kernel 0: curves + params + s0t0 + packed iw table -------
// thread g -> k = g&63 (coalesced), n = (g>>6)&63, b = g>>12
// ws_c  [b][j=n>>1][k][4] = {m2x_e, m2x_o, m2y_e, m2y_o}
// tbl4  [b][kk*32+cc]     = {a, b40, e0, e0*b40}   (kk,cc from idx=(n-32)*64+k)
__global__ __launch_bounds__(256)
void curve_prep(const float* __restrict__ pp, const float* __restrict__ iw_g,
                Rad12 rad,
                float* __restrict__ ws_c, float* __restrict__ params_ws,
                float2* __restrict__ st_ws, float4* __restrict__ tbl_ws)
{
    const int g = blockIdx.x * 256 + threadIdx.x;   // 16384 threads
    const int k = g & 63;
    const int n = (g >> 6) & 63;
    const int b = g >> 12;

#define PP(p) pp[((b * Pp) + (p)) * Kk + k]

    const int s  = n >> 4;
    const int it = n & 15;
    const float t = (float)it * 0.0625f;            // exact i/16
    const int s1 = (s + 1) & 3;

    float r0 = fabsf(PP(8 + 3 * s + 0));
    float r1 = fabsf(PP(8 + 3 * s + 1));
    float r2 = fabsf(PP(8 + 3 * s + 2));
    float r3 = fabsf(PP(8 + 3 * s1 + 0));
    float w1 = fabsf(PP(20 + 2 * s + 0));
    float w2 = fabsf(PP(20 + 2 * s + 1));

    float a0 = rad.v[3 * s + 0], a1 = rad.v[3 * s + 1];
    float a2 = rad.v[3 * s + 2], a3 = rad.v[3 * s1 + 0];

    float P0x = cosf(a0) * r0, P0y = sinf(a0) * r0;
    float P1x = cosf(a1) * r1, P1y = sinf(a1) * r1;
    float P2x = cosf(a2) * r2, P2y = sinf(a2) * r2;
    float P3x = cosf(a3) * r3, P3y = sinf(a3) * r3;

    float omt = 1.0f - t;
    float b0 = omt * omt * omt;
    float b1 = (3.0f * t) * (omt * omt);
    float b2 = (3.0f * (t * t)) * omt;
    float b3 = t * t * t;
    float bw1 = b1 * w1, bw2 = b2 * w2;
    float den = ((b0 + bw1) + bw2) + b3;
    float nx  = ((b0 * P0x + bw1 * P1x) + bw2 * P2x) + b3 * P3x;
    float ny  = ((b0 * P0y + bw1 * P1y) + bw2 * P2y) + b3 * P3y;

    float cx = nx / den, cy = ny / den;
    const int j = n >> 1, h = n & 1;
    float* base = ws_c + (((b * 32 + j) * 64) + k) * 4;
    base[h]     = -2.0f * cx;
    base[2 + h] = -2.0f * cy;

    if (n < 8) {
        float val;
        if (n < 4) {
            float q0 = PP(0), q1 = PP(1), q2 = PP(2), q3 = PP(3);
            float nrm = sqrtf(q0 * q0 + q1 * q1 + q2 * q2 + q3 * q3);
            val = PP(n) / nrm;
        } else {
            val = PP(n);        // p=4..6 trans, p=7 height
        }
        params_ws[(b * Kk + k) * 8 + n] = val;
    }
#undef PP

    // packed iw table for ph2: one b128 per (kk,cc)
    if (n >= 32) {
        const int idx = (n - 32) * 64 + k;          // 0..2047 = kk*32+cc
        float w  = iw_g[b * 2048 + idx];
        float a  = w * (-W40);
        float bb = (w - 1.0f) * W40;
        float e0 = fexp2(bb);
        tbl_ws[b * 2048 + idx] = make_float4(a, bb, e0, e0 * bb);
    }

    if (blockIdx.x == 0 && threadIdx.x < 128) {
        const int tb = threadIdx.x >> 5, tc = threadIdx.x & 31;
        float S = 0.0f, T = 0.0f;
        for (int kk = 0; kk < 64; ++kk) {
            float w   = iw_g[tb * 2048 + kk * 32 + tc];
            float b40 = (w - 1.0f) * W40;
            float e   = fexp2(b40);
            S += e;
            T  = fmaf(e, b40, T);
        }
        st_ws[threadIdx.x] = make_float2(S, T);
    }
}

// ---------------- Kernel 1: fused main, BARRIER-FREE after staging ---------
// block = 512 threads = 8 waves; each wave = 4 points (ph1 lane = primitive k).
// LDS exactly 32 KB (curves only). ONE barrier (post-staging); occ handoff via
// ds_bpermute (within-wave), iw tables via L2 b128 — waves desync after ph1 so
// epilogue/ph2 latency chains overlap other waves' ph1 FMA streams.
__global__ __launch_bounds__(512)
void csg_main(const float* __restrict__ pts, const float* __restrict__ uw_g,
              const int* __restrict__ flag,
              const float* __restrict__ ws_c, const float* __restrict__ params_ws,
              const float2* __restrict__ st_ws, const float4* __restrict__ tbl_ws,
              float* __restrict__ out)
{
    __shared__ __align__(16) float s_pool[8192];   // 32 KB exactly

    const int tid = threadIdx.x;
    const int bid = blockIdx.x;
    const int b   = bid >> 8;                  // 256 blocks per batch
    const int m0  = (bid & 255) << 5;          // 32 points per block

    {
        const float4* cs = (const float4*)(ws_c + (size_t)b * 8192);
        float4* cd = (float4*)s_pool;
#pragma unroll
        for (int i = 0; i < 4; ++i) cd[tid + i * 512] = cs[tid + i * 512];
    }
    __syncthreads();                           // the only barrier

    const int wid  = tid >> 6;
    const int lane = tid & 63;
    const int k    = lane;
    const int pt0  = b * Mm + m0 + (wid << 2);   // 4 pts per wave

    const float4* prm4 = (const float4*)(params_ws + ((b << 6) + k) * 8);
    float4 q4 = prm4[0];   // qw qx qy qz (normalized)
    float4 t4 = prm4[1];   // tx ty tz height

    const float4* pts4 = (const float4*)(pts + (size_t)pt0 * 3);
    float4 A = pts4[0], Bv = pts4[1], Cv = pts4[2];
    float pxs[4] = {A.x, A.w, Bv.z, Cv.y};
    float pys[4] = {A.y, Bv.x, Bv.w, Cv.z};
    float pzs[4] = {A.z, Bv.y, Cv.x, Cv.w};

    float px4[4], py4[4], plzv[4], psq[4];
    {
        float vx = -q4.y, vy = -q4.z, vz = -q4.w, qw = q4.x;
#pragma unroll
        for (int p = 0; p < 4; ++p) {
            float px = pxs[p] - t4.x, py = pys[p] - t4.y, pz = pzs[p] - t4.z;
            float t1x = 2.0f * (vy * pz - vz * py);
            float t1y = 2.0f * (vz * px - vx * pz);
            float t1z = 2.0f * (vx * py - vy * px);
            float plx = px + qw * t1x + (vy * t1z - vz * t1y);
            float ply = py + qw * t1y + (vz * t1x - vx * t1z);
            plzv[p] = pz + qw * t1z + (vx * t1y - vy * t1x);
            psq[p]  = plx * plx + ply * ply;
            px4[p]  = 4.0f * plx;                 // exact pow2 scale
            py4[p]  = 4.0f * ply;
        }
    }

    // 4x-scaled tracking (bit-exact vs unscaled; see R10 notes)
    float best4[4] = {1e30f, 1e30f, 1e30f, 1e30f};
    float bcsq4[4] = {0.0f, 0.0f, 0.0f, 0.0f};
    {
        const float4* cdp = (const float4*)&s_pool[k * 4];   // j*1024B imm
#pragma unroll 4
        for (int j = 0; j < 32; ++j) {
            float4 cd = cdp[j * 64];       // {m2x_e, m2x_o, m2y_e, m2y_o}
            float cq4x = fmaf(cd.x, cd.x, cd.z * cd.z);
            float cq4y = fmaf(cd.y, cd.y, cd.w * cd.w);
#pragma unroll
            for (int p = 0; p < 4; ++p) {
                float da = fmaf(cd.x, px4[p], fmaf(cd.z, py4[p], cq4x));
                if (da < best4[p]) { best4[p] = da; bcsq4[p] = cq4x; }
                float db = fmaf(cd.y, px4[p], fmaf(cd.w, py4[p], cq4y));
                if (db < best4[p]) { best4[p] = db; bcsq4[p] = cq4y; }
            }
        }
    }

    float occ[4];
    unsigned long long mu = 0ull;
#pragma unroll
    for (int p = 0; p < 4; ++p) {
        float d2    = psq[p] + 0.25f * best4[p];        // == psq + best exact
        float bq    = 0.25f * bcsq4[p];                 // == bcsq exact
        float ud    = sqrtf(fmaxf(d2, 0.0f) + 1e-12f);
        float sgn   = (psq[p] <= bq) ? -1.0f : 1.0f;    // == sqrt-compare
        float sdf2d = sgn * ud;
        float dzv   = fabsf(plzv[p]) - t4.w;
        float inner = fminf(fmaxf(sdf2d, dzv), 0.0f);
        float r1m   = fmaxf(sdf2d, 0.0f), r2m = fmaxf(dzv, 0.0f);
        float psdf  = inner + sqrtf(r1m * r1m + r2m * r2m + 1e-12f);
        out[OFF_PSDF + (pt0 + p) * Kk + k] = psdf;
        out[OFF_SD   + (pt0 + p) * Kk + k] = ud;
        occ[p]  = frcp(1.0f + fexp2(S75 * psdf));   // sigmoid(-75*psdf)
        mu |= __ballot(occ[p] > EPS_OCC);           // union over the 4 points
    }

    const int c  = lane & 31;
    const int hi = lane >> 5;                      // 0 = k<32, 1 = k>=32
    const int kb = hi << 5;
    float2 s0t0 = st_ws[b * 32 + c];
    const float4* tbl4 = tbl_ws + b * 2048;

    // ============ Phase 2: split-k across halves, NO barrier ==============
    const int training = flag[0];

    float inter[4];
    if (training) {
        float sw[4], swp[4];
#pragma unroll
        for (int p = 0; p < 4; ++p) {
            sw[p]  = hi ? 0.0f : s0t0.x;
            swp[p] = hi ? 0.0f : s0t0.y;
        }
        unsigned long long m = hi ? (mu >> 32) : (mu & 0xFFFFFFFFull);
        while (m) {
            int kk = __builtin_ctzll(m) + kb; m &= m - 1;
            int i4 = kk << 2;
            float o0 = bperm(i4, occ[0]);
            float o1 = bperm(i4, occ[1]);
            float o2 = bperm(i4, occ[2]);
            float o3 = bperm(i4, occ[3]);
            float4 wv = tbl4[kk * 32 + c];          // {a, b, e0, e0b} from L2
            float os[4] = {o0, o1, o2, o3};
#pragma unroll
            for (int p = 0; p < 4; ++p) {
                float pre = fmaf(wv.x, os[p], wv.y);    // -40*log2e * pre_i
                float e   = fexp2(pre);                 // in (0,1]: safe
                sw[p]  += (e - wv.z);
                swp[p] += fmaf(e, pre, -wv.w);
            }
        }
#pragma unroll
        for (int p = 0; p < 4; ++p) {
            float swt  = sw[p]  + __shfl_xor(sw[p], 32, 64);
            float swpt = swp[p] + __shfl_xor(swp[p], 32, 64);
            inter[p] = swpt * frcp(swt) * NL2_40;
        }
    } else {
        float mx[4] = {-1e30f, -1e30f, -1e30f, -1e30f};
#pragma unroll 4
        for (int j = 0; j < 32; ++j) {
            int kk = kb + j;
            int i4 = kk << 2;
            float4 wv = tbl4[kk * 32 + c];
            float os[4] = {bperm(i4, occ[0]), bperm(i4, occ[1]),
                           bperm(i4, occ[2]), bperm(i4, occ[3])};
#pragma unroll
            for (int p = 0; p < 4; ++p)
                mx[p] = fmaxf(mx[p], fmaf(wv.x, os[p], wv.y));
        }
#pragma unroll
        for (int p = 0; p < 4; ++p) {
            float m2 = fmaxf(mx[p], __shfl_xor(mx[p], 32, 64));
            inter[p] = m2 * NL2_40;                 // min_k pre_i
        }
    }

    if (lane < Cc) {
#pragma unroll
        for (int p = 0; p < 4; ++p)
            out[OFF_INTER + (pt0 + p) * Cc + c] = inter[p];
    }

    // ---- union over c (softmax / max) ----
    float uwv = uw_g[b * Cc + c];
    float resv[4];
    if (training) {
#pragma unroll
        for (int p = 0; p < 4; ++p) {
            float pu  = uwv * inter[p];
            float e   = fexp2(W40 * pu);             // exp(40*pre_u) <= e^40
            float num = e * pu, den = e;
#pragma unroll
            for (int msk = 16; msk >= 1; msk >>= 1) {
                num += __shfl_xor(num, msk, 64);
                den += __shfl_xor(den, msk, 64);
            }
            resv[p] = num * frcp(den);
        }
    } else {
#pragma unroll
        for (int p = 0; p < 4; ++p) {
            float pu = uwv * inter[p];
#pragma unroll
            for (int msk = 16; msk >= 1; msk >>= 1)
                pu = fmaxf(pu, __shfl_xor(pu, msk, 64));
            resv[p] = pu;
        }
    }
    if (lane == 0)
        *(float4*)(out + pt0) = make_float4(resv[0], resv[1], resv[2], resv[3]);
}

// ---------------- host launch ----------------------------------------------
extern "C" void kernel_launch(void* const* d_in, const int* in_sizes, int n_in,
                              void* d_out, int out_size, void* d_ws, size_t ws_size,
                              hipStream_t stream)
{
    const float* pts  = (const float*)d_in[0];
    const float* pp   = (const float*)d_in[1];
    const float* iw   = (const float*)d_in[2];
    const float* uw   = (const float*)d_in[3];
    const int*   flag = (const int*)d_in[4];
    float* out = (float*)d_out;

    float*  ws_c   = (float*)d_ws;                 // 32768 floats (128 KB)
    float*  params = ws_c + 32768;                 // 2048 floats (8 KB)
    float2* st_ws  = (float2*)(params + 2048);     // 128 float2 (1 KB)
    float4* tbl_ws = (float4*)((char*)d_ws + 140 * 1024);  // 8192 float4 (128 KB)

    Rad12 rad;
    const double th = M_PI * 2.0 / 16.0 + atan(tan(2.0 * M_PI / 16.0) / 3.0);
    for (int i = 0; i < 4; ++i) {
        double base = 2.0 * M_PI / 4.0 * (double)i;
        rad.v[3 * i + 0] = (float)base;
        rad.v[3 * i + 1] = (float)(base + th);
        rad.v[3 * i + 2] = (float)(2.0 * M_PI / 4.0 * (double)(i + 1) - th);
    }

    curve_prep<<<64, 256, 0, stream>>>(pp, iw, rad, ws_c, params, st_ws, tbl_ws);
    csg_main<<<Bb * Mm / 32, 512, 0, stream>>>(pts, uw, flag,
                                               ws_c, params, st_ws, tbl_ws, out);
}

// Round 18
// 38.961 us; speedup vs baseline: 2.1981x; 1.0185x over previous
//
#include <hip/hip_runtime.h>
#include <math.h>

#define Bb 4
#define Mm 8192
#define Kk 64
#define Cc 32
#define Pp 28

#define OFF_PSDF  (Bb*Mm)                          // 32768
#define OFF_INTER (Bb*Mm + Bb*Mm*Kk)               // 2129920
#define OFF_SD    (Bb*Mm + Bb*Mm*Kk + Bb*Mm*Cc)    // 3178496

#define W40    57.707801635558535f      // 40*log2(e)
#define NL2_40 (-0.017328679513998632f) // -ln2/40
#define S75    108.20212806667225f      // 75*log2(e)
#define EPS_OCC 1e-6f

struct Rad12 { float v[12]; };

__device__ __forceinline__ float fexp2(float x){ return __builtin_amdgcn_exp2f(x); }
__device__ __forceinline__ float frcp(float x){ return __builtin_amdgcn_rcpf(x); }
__device__ __forceinline__ float bperm(int idx4, float v){
    return __int_as_float(__builtin_amdgcn_ds_bpermute(idx4, __float_as_int(v)));
}

// ---------------- Kernel 0: curves + params + s0t0 + packed iw table -------
// thread g -> k = g&63 (coalesced), n = (g>>6)&63, b = g>>12
// ws_c  [b][j=n>>1][k][4] = {m2x_e, m2x_o, m2y_e, m2y_o}
// tbl4  [b][kk*32+cc]     = {a, b40, e0, e0*b40}
__global__ __launch_bounds__(256)
void curve_prep(const float* __restrict__ pp, const float* __restrict__ iw_g,
                Rad12 rad,
                float* __restrict__ ws_c, float* __restrict__ params_ws,
                float2* __restrict__ st_ws, float4* __restrict__ tbl_ws)
{
    const int g = blockIdx.x * 256 + threadIdx.x;   // 16384 threads
    const int k = g & 63;
    const int n = (g >> 6) & 63;
    const int b = g >> 12;

#define PP(p) pp[((b * Pp) + (p)) * Kk + k]

    const int s  = n >> 4;
    const int it = n & 15;
    const float t = (float)it * 0.0625f;            // exact i/16
    const int s1 = (s + 1) & 3;

    float r0 = fabsf(PP(8 + 3 * s + 0));
    float r1 = fabsf(PP(8 + 3 * s + 1));
    float r2 = fabsf(PP(8 + 3 * s + 2));
    float r3 = fabsf(PP(8 + 3 * s1 + 0));
    float w1 = fabsf(PP(20 + 2 * s + 0));
    float w2 = fabsf(PP(20 + 2 * s + 1));

    float a0 = rad.v[3 * s + 0], a1 = rad.v[3 * s + 1];
    float a2 = rad.v[3 * s + 2], a3 = rad.v[3 * s1 + 0];

    float P0x = cosf(a0) * r0, P0y = sinf(a0) * r0;
    float P1x = cosf(a1) * r1, P1y = sinf(a1) * r1;
    float P2x = cosf(a2) * r2, P2y = sinf(a2) * r2;
    float P3x = cosf(a3) * r3, P3y = sinf(a3) * r3;

    float omt = 1.0f - t;
    float b0 = omt * omt * omt;
    float b1 = (3.0f * t) * (omt * omt);
    float b2 = (3.0f * (t * t)) * omt;
    float b3 = t * t * t;
    float bw1 = b1 * w1, bw2 = b2 * w2;
    float den = ((b0 + bw1) + bw2) + b3;
    float nx  = ((b0 * P0x + bw1 * P1x) + bw2 * P2x) + b3 * P3x;
    float ny  = ((b0 * P0y + bw1 * P1y) + bw2 * P2y) + b3 * P3y;

    float cx = nx / den, cy = ny / den;
    const int j = n >> 1, h = n & 1;
    float* base = ws_c + (((b * 32 + j) * 64) + k) * 4;
    base[h]     = -2.0f * cx;
    base[2 + h] = -2.0f * cy;

    if (n < 8) {
        float val;
        if (n < 4) {
            float q0 = PP(0), q1 = PP(1), q2 = PP(2), q3 = PP(3);
            float nrm = sqrtf(q0 * q0 + q1 * q1 + q2 * q2 + q3 * q3);
            val = PP(n) / nrm;
        } else {
            val = PP(n);        // p=4..6 trans, p=7 height
        }
        params_ws[(b * Kk + k) * 8 + n] = val;
    }
#undef PP

    if (n >= 32) {
        const int idx = (n - 32) * 64 + k;          // 0..2047 = kk*32+cc
        float w  = iw_g[b * 2048 + idx];
        float a  = w * (-W40);
        float bb = (w - 1.0f) * W40;
        float e0 = fexp2(bb);
        tbl_ws[b * 2048 + idx] = make_float4(a, bb, e0, e0 * bb);
    }

    if (blockIdx.x == 0 && threadIdx.x < 128) {
        const int tb = threadIdx.x >> 5, tc = threadIdx.x & 31;
        float S = 0.0f, T = 0.0f;
        for (int kk = 0; kk < 64; ++kk) {
            float w   = iw_g[tb * 2048 + kk * 32 + tc];
            float b40 = (w - 1.0f) * W40;
            float e   = fexp2(b40);
            S += e;
            T  = fmaf(e, b40, T);
        }
        st_ws[threadIdx.x] = make_float2(S, T);
    }
}

// ---------------- Kernel 1: fused main, barrier-free after staging ---------
// block = 512 threads = 8 waves; wave = 4 points (ph1 lane = primitive k).
// Phase 2 split by POINT-PAIR: lo lanes (c=lane) own points 0,1 over the full
// k-mask; hi lanes own points 2,3 — no cross-half combine, half the exp2/bperm
// per lane vs k-half split.
__global__ __launch_bounds__(512)
void csg_main(const float* __restrict__ pts, const float* __restrict__ uw_g,
              const int* __restrict__ flag,
              const float* __restrict__ ws_c, const float* __restrict__ params_ws,
              const float2* __restrict__ st_ws, const float4* __restrict__ tbl_ws,
              float* __restrict__ out)
{
    __shared__ __align__(16) float s_pool[8192];   // 32 KB exactly

    const int tid = threadIdx.x;
    const int bid = blockIdx.x;
    const int b   = bid >> 8;                  // 256 blocks per batch
    const int m0  = (bid & 255) << 5;          // 32 points per block

    {
        const float4* cs = (const float4*)(ws_c + (size_t)b * 8192);
        float4* cd = (float4*)s_pool;
#pragma unroll
        for (int i = 0; i < 4; ++i) cd[tid + i * 512] = cs[tid + i * 512];
    }
    __syncthreads();                           // the only barrier

    const int wid  = tid >> 6;
    const int lane = tid & 63;
    const int k    = lane;
    const int pt0  = b * Mm + m0 + (wid << 2);   // 4 pts per wave

    const float4* prm4 = (const float4*)(params_ws + ((b << 6) + k) * 8);
    float4 q4 = prm4[0];   // qw qx qy qz (normalized)
    float4 t4 = prm4[1];   // tx ty tz height

    const float4* pts4 = (const float4*)(pts + (size_t)pt0 * 3);
    float4 A = pts4[0], Bv = pts4[1], Cv = pts4[2];
    float pxs[4] = {A.x, A.w, Bv.z, Cv.y};
    float pys[4] = {A.y, Bv.x, Bv.w, Cv.z};
    float pzs[4] = {A.z, Bv.y, Cv.x, Cv.w};

    float px4[4], py4[4], plzv[4], psq[4];
    {
        float vx = -q4.y, vy = -q4.z, vz = -q4.w, qw = q4.x;
#pragma unroll
        for (int p = 0; p < 4; ++p) {
            float px = pxs[p] - t4.x, py = pys[p] - t4.y, pz = pzs[p] - t4.z;
            float t1x = 2.0f * (vy * pz - vz * py);
            float t1y = 2.0f * (vz * px - vx * pz);
            float t1z = 2.0f * (vx * py - vy * px);
            float plx = px + qw * t1x + (vy * t1z - vz * t1y);
            float ply = py + qw * t1y + (vz * t1x - vx * t1z);
            plzv[p] = pz + qw * t1z + (vx * t1y - vy * t1x);
            psq[p]  = plx * plx + ply * ply;
            px4[p]  = 4.0f * plx;                 // exact pow2 scale
            py4[p]  = 4.0f * ply;
        }
    }

    // 4x-scaled tracking (bit-exact vs unscaled; see R10 notes)
    float best4[4] = {1e30f, 1e30f, 1e30f, 1e30f};
    float bcsq4[4] = {0.0f, 0.0f, 0.0f, 0.0f};
    {
        const float4* cdp = (const float4*)&s_pool[k * 4];   // j*1024B imm
#pragma unroll 4
        for (int j = 0; j < 32; ++j) {
            float4 cd = cdp[j * 64];       // {m2x_e, m2x_o, m2y_e, m2y_o}
            float cq4x = fmaf(cd.x, cd.x, cd.z * cd.z);
            float cq4y = fmaf(cd.y, cd.y, cd.w * cd.w);
#pragma unroll
            for (int p = 0; p < 4; ++p) {
                float da = fmaf(cd.x, px4[p], fmaf(cd.z, py4[p], cq4x));
                if (da < best4[p]) { best4[p] = da; bcsq4[p] = cq4x; }
                float db = fmaf(cd.y, px4[p], fmaf(cd.w, py4[p], cq4y));
                if (db < best4[p]) { best4[p] = db; bcsq4[p] = cq4y; }
            }
        }
    }

    float occ[4];
    unsigned long long msk[4];
#pragma unroll
    for (int p = 0; p < 4; ++p) {
        float d2    = psq[p] + 0.25f * best4[p];        // == psq + best exact
        float bq    = 0.25f * bcsq4[p];                 // == bcsq exact
        float ud    = sqrtf(fmaxf(d2, 0.0f) + 1e-12f);
        float sgn   = (psq[p] <= bq) ? -1.0f : 1.0f;    // == sqrt-compare
        float sdf2d = sgn * ud;
        float dzv   = fabsf(plzv[p]) - t4.w;
        float inner = fminf(fmaxf(sdf2d, dzv), 0.0f);
        float r1m   = fmaxf(sdf2d, 0.0f), r2m = fmaxf(dzv, 0.0f);
        float psdf  = inner + sqrtf(r1m * r1m + r2m * r2m + 1e-12f);
        out[OFF_PSDF + (pt0 + p) * Kk + k] = psdf;
        out[OFF_SD   + (pt0 + p) * Kk + k] = ud;
        occ[p]  = frcp(1.0f + fexp2(S75 * psdf));   // sigmoid(-75*psdf)
        msk[p]  = __ballot(occ[p] > EPS_OCC);
    }

    const int c  = lane & 31;
    const int hi = lane >> 5;                      // 0: points 0,1; 1: points 2,3
    float2 s0t0 = st_ws[b * 32 + c];
    const float4* tbl4 = tbl_ws + b * 2048;

    // my half's two points + their combined active mask (full 64 bits of k)
    const int pA = hi << 1, pB = pA + 1;
    float occA = occ[pA], occB = occ[pB];
    unsigned long long mpair = msk[pA] | msk[pB];

    // ============ Phase 2: split by point-pair, no cross-half combine ======
    const int training = flag[0];

    float interA, interB;
    if (training) {
        float swA = s0t0.x, swpA = s0t0.y;
        float swB = s0t0.x, swpB = s0t0.y;
        unsigned long long m = mpair;
        while (m) {
            int kk = __builtin_ctzll(m); m &= m - 1;
            int i4 = kk << 2;
            float oA = bperm(i4, occA);
            float oB = bperm(i4, occB);
            float4 wv = tbl4[kk * 32 + c];          // {a, b, e0, e0b} from L2
            float preA = fmaf(wv.x, oA, wv.y);      // -40*log2e * pre_i
            float preB = fmaf(wv.x, oB, wv.y);
            float eA = fexp2(preA), eB = fexp2(preB);
            swA  += (eA - wv.z);
            swpA += fmaf(eA, preA, -wv.w);
            swB  += (eB - wv.z);
            swpB += fmaf(eB, preB, -wv.w);
        }
        interA = swpA * frcp(swA) * NL2_40;
        interB = swpB * frcp(swB) * NL2_40;
    } else {
        float mxA = -1e30f, mxB = -1e30f;
#pragma unroll 4
        for (int kk = 0; kk < 64; ++kk) {
            int i4 = kk << 2;
            float oA = bperm(i4, occA);
            float oB = bperm(i4, occB);
            float4 wv = tbl4[kk * 32 + c];
            mxA = fmaxf(mxA, fmaf(wv.x, oA, wv.y));
            mxB = fmaxf(mxB, fmaf(wv.x, oB, wv.y));
        }
        interA = mxA * NL2_40;                      // min_k pre_i
        interB = mxB * NL2_40;
    }

    // inter store: all 64 lanes, 2 rows each (coalesced 128B per row)
    out[OFF_INTER + (pt0 + pA) * Cc + c] = interA;
    out[OFF_INTER + (pt0 + pB) * Cc + c] = interB;

    // ---- union over c (softmax / max), within each 32-lane half ----
    float uwv = uw_g[b * Cc + c];
    float resA, resB;
    if (training) {
        float puA = uwv * interA, puB = uwv * interB;
        float eA = fexp2(W40 * puA), eB = fexp2(W40 * puB);
        float numA = eA * puA, denA = eA;
        float numB = eB * puB, denB = eB;
#pragma unroll
        for (int mk = 16; mk >= 1; mk >>= 1) {      // stays within the half
            numA += __shfl_xor(numA, mk, 64);
            denA += __shfl_xor(denA, mk, 64);
            numB += __shfl_xor(numB, mk, 64);
            denB += __shfl_xor(denB, mk, 64);
        }
        resA = numA * frcp(denA);
        resB = numB * frcp(denB);
    } else {
        float puA = uwv * interA, puB = uwv * interB;
#pragma unroll
        for (int mk = 16; mk >= 1; mk >>= 1) {
            puA = fmaxf(puA, __shfl_xor(puA, mk, 64));
            puB = fmaxf(puB, __shfl_xor(puB, mk, 64));
        }
        resA = puA; resB = puB;
    }
    if (c == 0)   // lane 0 stores pts 0,1; lane 32 stores pts 2,3
        *(float2*)(out + pt0 + pA) = make_float2(resA, resB);
}

// ---------------- host launch ----------------------------------------------
extern "C" void kernel_launch(void* const* d_in, const int* in_sizes, int n_in,
                              void* d_out, int out_size, void* d_ws, size_t ws_size,
                              hipStream_t stream)
{
    const float* pts  = (const float*)d_in[0];
    const float* pp   = (const float*)d_in[1];
    const float* iw   = (const float*)d_in[2];
    const float* uw   = (const float*)d_in[3];
    const int*   flag = (const int*)d_in[4];
    float* out = (float*)d_out;

    float*  ws_c   = (float*)d_ws;                 // 32768 floats (128 KB)
    float*  params = ws_c + 32768;                 // 2048 floats (8 KB)
    float2* st_ws  = (float2*)(params + 2048);     // 128 float2 (1 KB)
    float4* tbl_ws = (float4*)((char*)d_ws + 140 * 1024);  // 8192 float4 (128 KB)

    Rad12 rad;
    const double th = M_PI * 2.0 / 16.0 + atan(tan(2.0 * M_PI / 16.0) / 3.0);
    for (int i = 0; i < 4; ++i) {
        double base = 2.0 * M_PI / 4.0 * (double)i;
        rad.v[3 * i + 0] = (float)base;
        rad.v[3 * i + 1] = (float)(base + th);
        rad.v[3 * i + 2] = (float)(2.0 * M_PI / 4.0 * (double)(i + 1) - th);
    }

    curve_prep<<<64, 256, 0, stream>>>(pp, iw, rad, ws_c, params, st_ws, tbl_ws);
    csg_main<<<Bb * Mm / 32, 512, 0, stream>>>(pts, uw, flag,
                                               ws_c, params, st_ws, tbl_ws, out);
}